// Round 7
// baseline (1778.524 us; speedup 1.0000x reference)
//
#include <hip/hip_runtime.h>
#include <hip/hip_bf16.h>

#define CHUNK 12288      // edges per partition block
#define NBIN_MAX 2048    // LDS bound for soc bins (n_user/64)
#define NBINM_MAX 1024   // marked bins (batch/16)
#define PB 6             // 64 users per soc bin
#define PBM 4            // 16 marked users per bin

__device__ __forceinline__ float bf2f(unsigned short u) {
    return __uint_as_float(((unsigned int)u) << 16);
}
__device__ __forceinline__ unsigned short f2bf(float f) {
    unsigned int x = __float_as_uint(f);
    return (unsigned short)((x + 0x7fffu + ((x >> 16) & 1u)) >> 16);  // RNE
}
__device__ __forceinline__ void unpack2(unsigned int u, float& lo, float& hi) {
    lo = __uint_as_float(u << 16);
    hi = __uint_as_float(u & 0xffff0000u);
}
__device__ __forceinline__ unsigned int pack2(float lo, float hi) {
    return (unsigned int)f2bf(lo) | ((unsigned int)f2bf(hi) << 16);
}

// ---------------- kernels ----------------

// f32 -> bf16 for user_emb and item_emb.
__global__ __launch_bounds__(256) void conv_kernel(const float* __restrict__ a,
                                                   unsigned short* __restrict__ oa, long long na,
                                                   const float* __restrict__ b,
                                                   unsigned short* __restrict__ ob, long long nb) {
    long long i4 = ((long long)blockIdx.x * blockDim.x + threadIdx.x) * 4;
    if (i4 < na) {
        float4 f = *(const float4*)&a[i4];
        ushort4 o = { f2bf(f.x), f2bf(f.y), f2bf(f.z), f2bf(f.w) };
        *(ushort4*)&oa[i4] = o;
    }
    if (i4 < nb) {
        float4 f = *(const float4*)&b[i4];
        ushort4 o = { f2bf(f.x), f2bf(f.y), f2bf(f.z), f2bf(f.w) };
        *(ushort4*)&ob[i4] = o;
    }
}

// Dedup-mark users in user_ids (mark[u]=compact+1) and init all bin cursors.
__global__ __launch_bounds__(256) void mark_init_kernel(const int* __restrict__ ids,
                                                        int* __restrict__ mark,
                                                        int* __restrict__ n_marked, int n,
                                                        int* __restrict__ curS, int nbinS, int capS,
                                                        int* __restrict__ curMS,
                                                        int* __restrict__ curMI, int capM) {
    int i = blockIdx.x * blockDim.x + threadIdx.x;
    if (i < nbinS) curS[i] = i * capS;
    if (i < NBINM_MAX) { curMS[i] = i * capM; curMI[i] = i * capM; }
    if (i < n) {
        int u = ids[i];
        if (atomicCAS(&mark[u], 0, -1) == 0) {
            int m = atomicAdd(n_marked, 1);
            mark[u] = m + 1;
        }
    }
}

// Phase A (soc): partition all soc edges into bins by row>>PB.
// Per-block LDS histogram -> one hot cursor atomic per (block,bin) -> contiguous chunk writes.
__global__ __launch_bounds__(256) void partA_soc(const int* __restrict__ rows,
                                                 const int* __restrict__ cols,
                                                 const float* __restrict__ vals,
                                                 int* __restrict__ cursor,
                                                 int2* __restrict__ buf, int E,
                                                 int nbin, int capb) {
    __shared__ int hist[NBIN_MAX], gbase[NBIN_MAX], lcur[NBIN_MAX];
    int tid = threadIdx.x;
    int base = blockIdx.x * CHUNK;
    int lim = min(base + CHUNK, E);
    for (int b = tid; b < nbin; b += 256) hist[b] = 0;
    __syncthreads();
    for (int i = base + tid; i < lim; i += 256) atomicAdd(&hist[rows[i] >> PB], 1);
    __syncthreads();
    for (int b = tid; b < nbin; b += 256) {
        int h = hist[b];
        gbase[b] = h ? atomicAdd(&cursor[b], h) : 0;
        lcur[b] = 0;
    }
    __syncthreads();
    for (int i = base + tid; i < lim; i += 256) {
        int r = rows[i];
        int b = r >> PB;
        int off = atomicAdd(&lcur[b], 1);
        long long dst = (long long)gbase[b] + off;
        if (dst < (long long)(b + 1) * capb)
            buf[dst] = make_int2(((r & 63) << 17) | cols[i], __float_as_int(vals[i]));
    }
}

// Phase A (marked): partition soc & info edges with marked rows into bins by compact>>PBM.
__global__ __launch_bounds__(256) void partA_m(const int* __restrict__ sr, const int* __restrict__ sc,
                                               const float* __restrict__ sv, int Es,
                                               const int* __restrict__ ir, const int* __restrict__ ic,
                                               const float* __restrict__ iv, int Ei,
                                               const int* __restrict__ mark,
                                               int* __restrict__ curS, int2* __restrict__ bufS,
                                               int* __restrict__ curI, int2* __restrict__ bufI,
                                               int capm) {
    __shared__ int hS[NBINM_MAX], gS[NBINM_MAX], lS[NBINM_MAX];
    __shared__ int hI[NBINM_MAX], gI[NBINM_MAX], lI[NBINM_MAX];
    int tid = threadIdx.x;
    int base = blockIdx.x * CHUNK;
    int limS = min(base + CHUNK, Es), limI = min(base + CHUNK, Ei);
    for (int b = tid; b < NBINM_MAX; b += 256) { hS[b] = 0; hI[b] = 0; }
    __syncthreads();
    for (int i = base + tid; i < limS; i += 256) {
        int m = mark[sr[i]];
        if (m > 0) atomicAdd(&hS[(m - 1) >> PBM], 1);
    }
    for (int i = base + tid; i < limI; i += 256) {
        int m = mark[ir[i]];
        if (m > 0) atomicAdd(&hI[(m - 1) >> PBM], 1);
    }
    __syncthreads();
    for (int b = tid; b < NBINM_MAX; b += 256) {
        int h = hS[b]; gS[b] = h ? atomicAdd(&curS[b], h) : 0; lS[b] = 0;
        h = hI[b];     gI[b] = h ? atomicAdd(&curI[b], h) : 0; lI[b] = 0;
    }
    __syncthreads();
    for (int i = base + tid; i < limS; i += 256) {
        int m = mark[sr[i]];
        if (m <= 0) continue;
        m -= 1;
        int b = m >> PBM;
        int off = atomicAdd(&lS[b], 1);
        long long dst = (long long)gS[b] + off;
        if (dst < (long long)(b + 1) * capm)
            bufS[dst] = make_int2(((m & 15) << 17) | sc[i], __float_as_int(sv[i]));
    }
    for (int i = base + tid; i < limI; i += 256) {
        int m = mark[ir[i]];
        if (m <= 0) continue;
        m -= 1;
        int b = m >> PBM;
        int off = atomicAdd(&lI[b], 1);
        long long dst = (long long)gI[b] + off;
        if (dst < (long long)(b + 1) * capm)
            bufI[dst] = make_int2(((m & 15) << 17) | ic[i], __float_as_int(iv[i]));
    }
}

// Phase B (h1): one block per soc bin; accumulate 64 users' h1 rows in LDS (f32),
// then h1[r] = acc/deg + ub[r], written as bf16. 8 lanes per edge (16B each).
__global__ __launch_bounds__(256) void partB_h1(const int* __restrict__ cursor,
                                                const int2* __restrict__ buf,
                                                const unsigned short* __restrict__ ub,
                                                unsigned short* __restrict__ hb,
                                                int n_user, int capb) {
    int bin = blockIdx.x;
    int rows0 = bin << PB;
    int nrows = min(64, n_user - rows0);
    __shared__ float hacc[64][65];
    __shared__ float deg[64];
    int tid = threadIdx.x;
    for (int i = tid; i < 64 * 65; i += 256) ((float*)hacc)[i] = 0.f;
    if (tid < 64) deg[tid] = 0.f;
    __syncthreads();
    long long gstart = (long long)bin * capb;
    long long gend = cursor[bin];
    long long gcap = gstart + capb;
    if (gend > gcap) gend = gcap;
    int sg = tid >> 3;        // 32 edge slots per block
    int ln = tid & 7;
    int d8 = ln << 3;
    for (long long j = gstart + sg; j < gend; j += 32) {
        int2 e = buf[j];
        int c = e.x & 0x1FFFF;
        int rl = e.x >> 17;
        float v = __int_as_float(e.y);
        int4 q = *(const int4*)&ub[(long long)c * 64 + d8];
        float f0, f1, f2, f3, f4, f5, f6, f7;
        unpack2(q.x, f0, f1); unpack2(q.y, f2, f3);
        unpack2(q.z, f4, f5); unpack2(q.w, f6, f7);
        float* hr = &hacc[rl][d8];
        unsafeAtomicAdd(hr + 0, v * f0); unsafeAtomicAdd(hr + 1, v * f1);
        unsafeAtomicAdd(hr + 2, v * f2); unsafeAtomicAdd(hr + 3, v * f3);
        unsafeAtomicAdd(hr + 4, v * f4); unsafeAtomicAdd(hr + 5, v * f5);
        unsafeAtomicAdd(hr + 6, v * f6); unsafeAtomicAdd(hr + 7, v * f7);
        if (ln == 0) unsafeAtomicAdd(&deg[rl], v);
    }
    __syncthreads();
    for (int idx = tid; idx < nrows * 8; idx += 256) {
        int r = idx >> 3, dd = (idx & 7) << 3;
        float inv = 1.0f / (deg[r] + 1e-8f);
        int4 q = *(const int4*)&ub[(long long)(rows0 + r) * 64 + dd];
        float g0, g1, g2, g3, g4, g5, g6, g7;
        unpack2(q.x, g0, g1); unpack2(q.y, g2, g3);
        unpack2(q.z, g4, g5); unpack2(q.w, g6, g7);
        const float* hr = &hacc[r][dd];
        int4 o;
        o.x = (int)pack2(fmaf(hr[0], inv, g0), fmaf(hr[1], inv, g1));
        o.y = (int)pack2(fmaf(hr[2], inv, g2), fmaf(hr[3], inv, g3));
        o.z = (int)pack2(fmaf(hr[4], inv, g4), fmaf(hr[5], inv, g5));
        o.w = (int)pack2(fmaf(hr[6], inv, g6), fmaf(hr[7], inv, g7));
        *(int4*)&hb[(long long)(rows0 + r) * 64 + dd] = o;
    }
}

// Phase B (accF): one block per marked bin (16 users); soc part gathers h1 (bf16),
// info part gathers item_emb (bf16); accF[m] = sS/degS + sI/degI (f32, compact).
__global__ __launch_bounds__(256) void partB_accF(const int* __restrict__ n_marked,
                                                  const int* __restrict__ curS,
                                                  const int2* __restrict__ bufS,
                                                  const unsigned short* __restrict__ hb,
                                                  const int* __restrict__ curI,
                                                  const int2* __restrict__ bufI,
                                                  const unsigned short* __restrict__ ib,
                                                  float* __restrict__ accF, int capm) {
    int bin = blockIdx.x;
    int nm = *n_marked;
    int rows0 = bin << PBM;
    if (rows0 >= nm) return;
    int nrows = min(16, nm - rows0);
    __shared__ float aS[16][65], aI[16][65];
    __shared__ float dS[16], dI[16];
    int tid = threadIdx.x;
    for (int i = tid; i < 16 * 65; i += 256) { ((float*)aS)[i] = 0.f; ((float*)aI)[i] = 0.f; }
    if (tid < 16) { dS[tid] = 0.f; dI[tid] = 0.f; }
    __syncthreads();
    int sg = tid >> 3, ln = tid & 7, d8 = ln << 3;

    long long gstart = (long long)bin * capm;
    long long gend = curS[bin];
    if (gend > gstart + capm) gend = gstart + capm;
    for (long long j = gstart + sg; j < gend; j += 32) {
        int2 e = bufS[j];
        int c = e.x & 0x1FFFF;
        int rl = e.x >> 17;
        float v = __int_as_float(e.y);
        int4 q = *(const int4*)&hb[(long long)c * 64 + d8];
        float f0, f1, f2, f3, f4, f5, f6, f7;
        unpack2(q.x, f0, f1); unpack2(q.y, f2, f3);
        unpack2(q.z, f4, f5); unpack2(q.w, f6, f7);
        float* ar = &aS[rl][d8];
        unsafeAtomicAdd(ar + 0, v * f0); unsafeAtomicAdd(ar + 1, v * f1);
        unsafeAtomicAdd(ar + 2, v * f2); unsafeAtomicAdd(ar + 3, v * f3);
        unsafeAtomicAdd(ar + 4, v * f4); unsafeAtomicAdd(ar + 5, v * f5);
        unsafeAtomicAdd(ar + 6, v * f6); unsafeAtomicAdd(ar + 7, v * f7);
        if (ln == 0) unsafeAtomicAdd(&dS[rl], v);
    }
    gstart = (long long)bin * capm;
    gend = curI[bin];
    if (gend > gstart + capm) gend = gstart + capm;
    for (long long j = gstart + sg; j < gend; j += 32) {
        int2 e = bufI[j];
        int c = e.x & 0x1FFFF;
        int rl = e.x >> 17;
        float v = __int_as_float(e.y);
        int4 q = *(const int4*)&ib[(long long)c * 64 + d8];
        float f0, f1, f2, f3, f4, f5, f6, f7;
        unpack2(q.x, f0, f1); unpack2(q.y, f2, f3);
        unpack2(q.z, f4, f5); unpack2(q.w, f6, f7);
        float* ar = &aI[rl][d8];
        unsafeAtomicAdd(ar + 0, v * f0); unsafeAtomicAdd(ar + 1, v * f1);
        unsafeAtomicAdd(ar + 2, v * f2); unsafeAtomicAdd(ar + 3, v * f3);
        unsafeAtomicAdd(ar + 4, v * f4); unsafeAtomicAdd(ar + 5, v * f5);
        unsafeAtomicAdd(ar + 6, v * f6); unsafeAtomicAdd(ar + 7, v * f7);
        if (ln == 0) unsafeAtomicAdd(&dI[rl], v);
    }
    __syncthreads();
    for (int idx = tid; idx < nrows * 8; idx += 256) {
        int r = idx >> 3, dd = (idx & 7) << 3;
        float invS = 1.0f / (dS[r] + 1e-8f);
        float invI = 1.0f / (dI[r] + 1e-8f);
        float* pS = &aS[r][dd];
        float* pI = &aI[r][dd];
        long long base = (long long)(rows0 + r) * 64 + dd;
        float4 o0 = { pS[0] * invS + pI[0] * invI, pS[1] * invS + pI[1] * invI,
                      pS[2] * invS + pI[2] * invI, pS[3] * invS + pI[3] * invI };
        float4 o1 = { pS[4] * invS + pI[4] * invI, pS[5] * invS + pI[5] * invI,
                      pS[6] * invS + pI[6] * invI, pS[7] * invS + pI[7] * invI };
        *(float4*)&accF[base] = o0;
        *(float4*)&accF[base + 4] = o1;
    }
}

// out[i] = sigmoid( dot(2*h1[uid] + accF[mark[uid]-1], 2*item_emb[iid]) )
__global__ __launch_bounds__(256) void dot_kernel(const unsigned short* __restrict__ hb,
                                                  const float* __restrict__ accF,
                                                  const unsigned short* __restrict__ ib,
                                                  const int* __restrict__ mark,
                                                  const int* __restrict__ uids,
                                                  const int* __restrict__ iids,
                                                  float* __restrict__ out, int batch) {
    int w = (int)((blockIdx.x * (long long)blockDim.x + threadIdx.x) >> 6);
    int lane = threadIdx.x & 63;
    if (w >= batch) return;
    int u = uids[w], it = iids[w];
    int m = mark[u] - 1;
    float uv = 2.0f * bf2f(hb[(long long)u * 64 + lane]) + accF[(long long)m * 64 + lane];
    float vv = 2.0f * bf2f(ib[(long long)it * 64 + lane]);
    float p = uv * vv;
    #pragma unroll
    for (int off = 32; off; off >>= 1) p += __shfl_xor(p, off);
    if (lane == 0) out[w] = 1.0f / (1.0f + __expf(-p));
}

// ---------------- launch ----------------

extern "C" void kernel_launch(void* const* d_in, const int* in_sizes, int n_in,
                              void* d_out, int out_size, void* d_ws, size_t ws_size,
                              hipStream_t stream) {
    const float* user_emb  = (const float*)d_in[0];
    const float* item_emb  = (const float*)d_in[1];
    const int*   soc_rows  = (const int*)d_in[2];
    const int*   soc_cols  = (const int*)d_in[3];
    const float* soc_vals  = (const float*)d_in[4];
    const int*   info_rows = (const int*)d_in[5];
    const int*   info_cols = (const int*)d_in[6];
    const float* info_vals = (const float*)d_in[7];
    const int*   user_ids  = (const int*)d_in[8];
    const int*   item_ids  = (const int*)d_in[9];
    float*       out       = (float*)d_out;

    const int n_user = in_sizes[0] / 64;
    const int n_item = in_sizes[1] / 64;
    const int E_soc  = in_sizes[2];
    const int E_info = in_sizes[5];
    const int batch  = in_sizes[8];

    const int nbinS = (n_user + 63) >> PB;                     // 1563
    const int meanS = (int)((long long)E_soc * 64 / n_user);   // ~2048
    const int capS  = meanS + meanS / 4 + 64;                  // ~11 sigma headroom
    const int Emax  = max(E_soc, E_info);
    const int meanM = (int)((long long)Emax * 16 / n_user);    // ~512
    const int capM  = meanM + meanM / 2 + 64;                  // ~14 sigma headroom

    // ---- workspace layout ----
    char* p = (char*)d_ws;
    auto alloc = [&](size_t bytes) { char* q = p; p += (bytes + 255) & ~size_t(255); return q; };
    // zeroed region (contiguous at front)
    int* mark     = (int*)alloc(sizeof(int) * n_user);
    int* n_marked = (int*)alloc(sizeof(int) * 64);
    size_t zero_bytes = (size_t)(p - (char*)d_ws);
    // non-zeroed
    int*  curSoc = (int*)alloc(sizeof(int) * nbinS);
    int*  curMS  = (int*)alloc(sizeof(int) * NBINM_MAX);
    int*  curMI  = (int*)alloc(sizeof(int) * NBINM_MAX);
    int2* bufSoc = (int2*)alloc(sizeof(int2) * (size_t)nbinS * capS);     // ~33 MB
    int2* bufMS  = (int2*)alloc(sizeof(int2) * (size_t)NBINM_MAX * capM); // ~7 MB
    int2* bufMI  = (int2*)alloc(sizeof(int2) * (size_t)NBINM_MAX * capM); // ~7 MB
    unsigned short* ub = (unsigned short*)alloc(sizeof(short) * (size_t)n_user * 64);
    unsigned short* ib = (unsigned short*)alloc(sizeof(short) * (size_t)n_item * 64);
    unsigned short* hb = (unsigned short*)alloc(sizeof(short) * (size_t)n_user * 64);
    float* accF        = (float*)alloc(sizeof(float) * (size_t)batch * 64);
    (void)ws_size;

    hipMemsetAsync(d_ws, 0, zero_bytes, stream);

    const int B = 256;
    long long na = (long long)n_user * 64, nbm = (long long)n_item * 64;
    long long c4 = (na > nbm ? na : nbm) / 4;
    conv_kernel<<<(int)((c4 + B - 1) / B), B, 0, stream>>>(user_emb, ub, na, item_emb, ib, nbm);

    mark_init_kernel<<<(batch + B - 1) / B, B, 0, stream>>>(user_ids, mark, n_marked, batch,
                                                            curSoc, nbinS, capS, curMS, curMI, capM);

    int gA = (E_soc + CHUNK - 1) / CHUNK;
    partA_soc<<<gA, B, 0, stream>>>(soc_rows, soc_cols, soc_vals, curSoc, bufSoc,
                                    E_soc, nbinS, capS);

    int gAm = (Emax + CHUNK - 1) / CHUNK;
    partA_m<<<gAm, B, 0, stream>>>(soc_rows, soc_cols, soc_vals, E_soc,
                                   info_rows, info_cols, info_vals, E_info,
                                   mark, curMS, bufMS, curMI, bufMI, capM);

    partB_h1<<<nbinS, B, 0, stream>>>(curSoc, bufSoc, ub, hb, n_user, capS);

    int gBm = (batch + 15) >> PBM;   // upper bound on marked bins
    partB_accF<<<gBm, B, 0, stream>>>(n_marked, curMS, bufMS, hb, curMI, bufMI, ib, accF, capM);

    long long t2 = (long long)batch * 64;
    dot_kernel<<<(int)((t2 + B - 1) / B), B, 0, stream>>>(hb, accF, ib, mark,
                                                          user_ids, item_ids, out, batch);
}

// Round 8
// 294.945 us; speedup vs baseline: 6.0300x; 6.0300x over previous
//
#include <hip/hip_runtime.h>
#include <hip/hip_bf16.h>

#define CHUNK 12288       // edges per partition block
#define NBIN_MAX 2048     // soc bins LDS bound (n_user/64)
#define NBINM_MAX 1024    // marked bins LDS bound (batch/16)
#define PB 6              // 64 users per soc bin
#define PBM 4             // 16 marked users per bin
#define CAPS_LDS 2624     // soc bin capacity (mean 2048 + ~12 sigma)
#define CAPM_LDS 832      // marked bin capacity (mean 512 + ~14 sigma)

__device__ __forceinline__ float bf2f(unsigned short u) {
    return __uint_as_float(((unsigned int)u) << 16);
}
__device__ __forceinline__ unsigned short f2bf(float f) {
    unsigned int x = __float_as_uint(f);
    return (unsigned short)((x + 0x7fffu + ((x >> 16) & 1u)) >> 16);  // RNE
}

// ---------------- kernels ----------------

// f32 -> bf16 for user_emb and item_emb.
__global__ __launch_bounds__(256) void conv_kernel(const float* __restrict__ a,
                                                   unsigned short* __restrict__ oa, long long na,
                                                   const float* __restrict__ b,
                                                   unsigned short* __restrict__ ob, long long nb) {
    long long i4 = ((long long)blockIdx.x * blockDim.x + threadIdx.x) * 4;
    if (i4 < na) {
        float4 f = *(const float4*)&a[i4];
        ushort4 o = { f2bf(f.x), f2bf(f.y), f2bf(f.z), f2bf(f.w) };
        *(ushort4*)&oa[i4] = o;
    }
    if (i4 < nb) {
        float4 f = *(const float4*)&b[i4];
        ushort4 o = { f2bf(f.x), f2bf(f.y), f2bf(f.z), f2bf(f.w) };
        *(ushort4*)&ob[i4] = o;
    }
}

// Dedup-mark users (mark[u]=compact+1) and init bin cursors.
__global__ __launch_bounds__(256) void mark_init_kernel(const int* __restrict__ ids,
                                                        int* __restrict__ mark,
                                                        int* __restrict__ n_marked, int n,
                                                        int* __restrict__ curS, int nbinS, int capS,
                                                        int* __restrict__ curMI, int capM) {
    int i = blockIdx.x * blockDim.x + threadIdx.x;
    if (i < nbinS) curS[i] = i * capS;
    if (i < NBINM_MAX) curMI[i] = i * capM;
    if (i < n) {
        int u = ids[i];
        if (atomicCAS(&mark[u], 0, -1) == 0) {
            int m = atomicAdd(n_marked, 1);
            mark[u] = m + 1;
        }
    }
}

// Phase A (soc): partition all soc edges into bins by row>>PB.
__global__ __launch_bounds__(256) void partA_soc(const int* __restrict__ rows,
                                                 const int* __restrict__ cols,
                                                 const float* __restrict__ vals,
                                                 int* __restrict__ cursor,
                                                 int2* __restrict__ buf, int E,
                                                 int nbin, int capb) {
    __shared__ int hist[NBIN_MAX], gbase[NBIN_MAX], lcur[NBIN_MAX];
    int tid = threadIdx.x;
    int base = blockIdx.x * CHUNK;
    int lim = min(base + CHUNK, E);
    for (int b = tid; b < nbin; b += 256) hist[b] = 0;
    __syncthreads();
    for (int i = base + tid; i < lim; i += 256) atomicAdd(&hist[rows[i] >> PB], 1);
    __syncthreads();
    for (int b = tid; b < nbin; b += 256) {
        int h = hist[b];
        gbase[b] = h ? atomicAdd(&cursor[b], h) : 0;
        lcur[b] = 0;
    }
    __syncthreads();
    for (int i = base + tid; i < lim; i += 256) {
        int r = rows[i];
        int b = r >> PB;
        int off = atomicAdd(&lcur[b], 1);
        long long dst = (long long)gbase[b] + off;
        if (dst < (long long)(b + 1) * capb)
            buf[dst] = make_int2(((r & 63) << 17) | cols[i], __float_as_int(vals[i]));
    }
}

// Phase A (info): partition info edges with marked rows into bins by compact>>PBM.
__global__ __launch_bounds__(256) void partA_info(const int* __restrict__ ir,
                                                  const int* __restrict__ ic,
                                                  const float* __restrict__ iv, int Ei,
                                                  const int* __restrict__ mark,
                                                  int* __restrict__ cur,
                                                  int2* __restrict__ buf, int capm) {
    __shared__ int hist[NBINM_MAX], gbase[NBINM_MAX], lcur[NBINM_MAX];
    int tid = threadIdx.x;
    int base = blockIdx.x * CHUNK;
    int lim = min(base + CHUNK, Ei);
    for (int b = tid; b < NBINM_MAX; b += 256) hist[b] = 0;
    __syncthreads();
    for (int i = base + tid; i < lim; i += 256) {
        int m = mark[ir[i]];
        if (m > 0) atomicAdd(&hist[(m - 1) >> PBM], 1);
    }
    __syncthreads();
    for (int b = tid; b < NBINM_MAX; b += 256) {
        int h = hist[b];
        gbase[b] = h ? atomicAdd(&cur[b], h) : 0;
        lcur[b] = 0;
    }
    __syncthreads();
    for (int i = base + tid; i < lim; i += 256) {
        int m = mark[ir[i]];
        if (m <= 0) continue;
        m -= 1;
        int b = m >> PBM;
        int off = atomicAdd(&lcur[b], 1);
        long long dst = (long long)gbase[b] + off;
        if (dst < (long long)(b + 1) * capm)
            buf[dst] = make_int2(((m & 15) << 17) | ic[i], __float_as_int(iv[i]));
    }
}

// Phase B (h1): per soc bin, LDS counting-sort by local row, then register-accum gather.
// h1[r] = (sum val*ub[col])/(sum val+eps) + ub[r], bf16 out. NO float atomics.
__global__ __launch_bounds__(256) void partB_h1(const int* __restrict__ cursor,
                                                const int2* __restrict__ buf,
                                                const unsigned short* __restrict__ ub,
                                                unsigned short* __restrict__ hb,
                                                int n_user, int capb) {
    int bin = blockIdx.x;
    int rows0 = bin << PB;
    int nrows = min(64, n_user - rows0);
    __shared__ int2 sorted[CAPS_LDS];
    __shared__ int j0[65];
    __shared__ int cur[64];
    int tid = threadIdx.x;
    if (tid < 64) cur[tid] = 0;
    __syncthreads();
    long long gstart = (long long)bin * capb;
    long long gend = cursor[bin];
    if (gend > gstart + capb) gend = gstart + capb;
    int cnt = (int)(gend - gstart);
    for (int i = tid; i < cnt; i += 256) atomicAdd(&cur[buf[gstart + i].x >> 17], 1);
    __syncthreads();
    if (tid < 64) {
        int x = cur[tid];
        int v = x;
        #pragma unroll
        for (int d = 1; d < 64; d <<= 1) { int y = __shfl_up(v, d); if (tid >= d) v += y; }
        j0[tid] = v - x;
        cur[tid] = v - x;
        if (tid == 63) j0[64] = v;
    }
    __syncthreads();
    for (int i = tid; i < cnt; i += 256) {
        int2 e = buf[gstart + i];
        int rl = e.x >> 17;
        int p = atomicAdd(&cur[rl], 1);
        sorted[p] = make_int2(e.x & 0x1FFFF, e.y);
    }
    __syncthreads();
    int wid = tid >> 6, lane = tid & 63;
    int sub = lane >> 4, d4 = (lane & 15) << 2;
    for (int r = wid; r < nrows; r += 4) {
        int a = j0[r], b2 = j0[r + 1];
        float4 acc = make_float4(0.f, 0.f, 0.f, 0.f);
        float degs = 0.f;
        for (int j = a + sub; j < b2; j += 4) {
            int2 e = sorted[j];
            float v = __int_as_float(e.y);
            ushort4 q = *(const ushort4*)&ub[(long long)e.x * 64 + d4];
            acc.x += v * bf2f(q.x); acc.y += v * bf2f(q.y);
            acc.z += v * bf2f(q.z); acc.w += v * bf2f(q.w);
            degs += v;
        }
        #pragma unroll
        for (int m = 16; m < 64; m <<= 1) {
            acc.x += __shfl_xor(acc.x, m); acc.y += __shfl_xor(acc.y, m);
            acc.z += __shfl_xor(acc.z, m); acc.w += __shfl_xor(acc.w, m);
            degs  += __shfl_xor(degs, m);
        }
        if (sub == 0) {
            float inv = 1.0f / (degs + 1e-8f);
            ushort4 qe = *(const ushort4*)&ub[(long long)(rows0 + r) * 64 + d4];
            ushort4 o = { f2bf(fmaf(acc.x, inv, bf2f(qe.x))),
                          f2bf(fmaf(acc.y, inv, bf2f(qe.y))),
                          f2bf(fmaf(acc.z, inv, bf2f(qe.z))),
                          f2bf(fmaf(acc.w, inv, bf2f(qe.w))) };
            *(ushort4*)&hb[(long long)(rows0 + r) * 64 + d4] = o;
        }
    }
}

// Phase B (accS): re-scan soc bins, keep edges with marked rows, sort, gather h1.
// accS[m] = (sum val*h1[col])/(sum val+eps), f32 compact.
__global__ __launch_bounds__(256) void partB_accS(const int* __restrict__ mark,
                                                  const int* __restrict__ cursor,
                                                  const int2* __restrict__ buf,
                                                  const unsigned short* __restrict__ hb,
                                                  float* __restrict__ accS,
                                                  int n_user, int capb) {
    int bin = blockIdx.x;
    int rows0 = bin << PB;
    int nrows = min(64, n_user - rows0);
    __shared__ int2 sorted[CAPS_LDS];
    __shared__ int j0[65];
    __shared__ int cur[64];
    __shared__ int mrow[64];
    int tid = threadIdx.x;
    if (tid < 64) {
        mrow[tid] = (tid < nrows) ? mark[rows0 + tid] : 0;
        cur[tid] = 0;
    }
    __syncthreads();
    long long gstart = (long long)bin * capb;
    long long gend = cursor[bin];
    if (gend > gstart + capb) gend = gstart + capb;
    int cnt = (int)(gend - gstart);
    for (int i = tid; i < cnt; i += 256) {
        int rl = buf[gstart + i].x >> 17;
        if (mrow[rl] > 0) atomicAdd(&cur[rl], 1);
    }
    __syncthreads();
    if (tid < 64) {
        int x = cur[tid];
        int v = x;
        #pragma unroll
        for (int d = 1; d < 64; d <<= 1) { int y = __shfl_up(v, d); if (tid >= d) v += y; }
        j0[tid] = v - x;
        cur[tid] = v - x;
        if (tid == 63) j0[64] = v;
    }
    __syncthreads();
    for (int i = tid; i < cnt; i += 256) {
        int2 e = buf[gstart + i];
        int rl = e.x >> 17;
        if (mrow[rl] <= 0) continue;
        int p = atomicAdd(&cur[rl], 1);
        sorted[p] = make_int2(e.x & 0x1FFFF, e.y);
    }
    __syncthreads();
    int wid = tid >> 6, lane = tid & 63;
    int sub = lane >> 4, d4 = (lane & 15) << 2;
    for (int r = wid; r < nrows; r += 4) {
        int mm = mrow[r];
        if (mm <= 0) continue;
        int a = j0[r], b2 = j0[r + 1];
        float4 acc = make_float4(0.f, 0.f, 0.f, 0.f);
        float degs = 0.f;
        for (int j = a + sub; j < b2; j += 4) {
            int2 e = sorted[j];
            float v = __int_as_float(e.y);
            ushort4 q = *(const ushort4*)&hb[(long long)e.x * 64 + d4];
            acc.x += v * bf2f(q.x); acc.y += v * bf2f(q.y);
            acc.z += v * bf2f(q.z); acc.w += v * bf2f(q.w);
            degs += v;
        }
        #pragma unroll
        for (int m = 16; m < 64; m <<= 1) {
            acc.x += __shfl_xor(acc.x, m); acc.y += __shfl_xor(acc.y, m);
            acc.z += __shfl_xor(acc.z, m); acc.w += __shfl_xor(acc.w, m);
            degs  += __shfl_xor(degs, m);
        }
        if (sub == 0) {
            float inv = 1.0f / (degs + 1e-8f);
            float4 o = make_float4(acc.x * inv, acc.y * inv, acc.z * inv, acc.w * inv);
            *(float4*)&accS[(long long)(mm - 1) * 64 + d4] = o;
        }
    }
}

// Phase B (accI): per marked bin (16 users), sort by local idx, gather item_emb.
// accI[m] = (sum val*ib[col])/(sum val+eps), f32 compact.
__global__ __launch_bounds__(256) void partB_accI(const int* __restrict__ n_marked,
                                                  const int* __restrict__ cur_in,
                                                  const int2* __restrict__ buf,
                                                  const unsigned short* __restrict__ ib,
                                                  float* __restrict__ accI, int capm) {
    int bin = blockIdx.x;
    int nm = *n_marked;
    int rows0 = bin << PBM;
    if (rows0 >= nm) return;
    int nrows = min(16, nm - rows0);
    __shared__ int2 sorted[CAPM_LDS];
    __shared__ int j0[17];
    __shared__ int cur[16];
    int tid = threadIdx.x;
    if (tid < 16) cur[tid] = 0;
    __syncthreads();
    long long gstart = (long long)bin * capm;
    long long gend = cur_in[bin];
    if (gend > gstart + capm) gend = gstart + capm;
    int cnt = (int)(gend - gstart);
    for (int i = tid; i < cnt; i += 256) atomicAdd(&cur[buf[gstart + i].x >> 17], 1);
    __syncthreads();
    if (tid < 16) {
        int x = cur[tid];
        int v = x;
        #pragma unroll
        for (int d = 1; d < 16; d <<= 1) { int y = __shfl_up(v, d); if (tid >= d) v += y; }
        j0[tid] = v - x;
        cur[tid] = v - x;
        if (tid == 15) j0[16] = v;
    }
    __syncthreads();
    for (int i = tid; i < cnt; i += 256) {
        int2 e = buf[gstart + i];
        int rl = e.x >> 17;
        int p = atomicAdd(&cur[rl], 1);
        sorted[p] = make_int2(e.x & 0x1FFFF, e.y);
    }
    __syncthreads();
    int wid = tid >> 6, lane = tid & 63;
    int sub = lane >> 4, d4 = (lane & 15) << 2;
    for (int r = wid; r < nrows; r += 4) {
        int a = j0[r], b2 = j0[r + 1];
        float4 acc = make_float4(0.f, 0.f, 0.f, 0.f);
        float degs = 0.f;
        for (int j = a + sub; j < b2; j += 4) {
            int2 e = sorted[j];
            float v = __int_as_float(e.y);
            ushort4 q = *(const ushort4*)&ib[(long long)e.x * 64 + d4];
            acc.x += v * bf2f(q.x); acc.y += v * bf2f(q.y);
            acc.z += v * bf2f(q.z); acc.w += v * bf2f(q.w);
            degs += v;
        }
        #pragma unroll
        for (int m = 16; m < 64; m <<= 1) {
            acc.x += __shfl_xor(acc.x, m); acc.y += __shfl_xor(acc.y, m);
            acc.z += __shfl_xor(acc.z, m); acc.w += __shfl_xor(acc.w, m);
            degs  += __shfl_xor(degs, m);
        }
        if (sub == 0) {
            float inv = 1.0f / (degs + 1e-8f);
            float4 o = make_float4(acc.x * inv, acc.y * inv, acc.z * inv, acc.w * inv);
            *(float4*)&accI[(long long)(rows0 + r) * 64 + d4] = o;
        }
    }
}

// out[i] = sigmoid( dot(2*h1[uid] + accS[m] + accI[m], 2*item_emb[iid]) )
__global__ __launch_bounds__(256) void dot_kernel(const unsigned short* __restrict__ hb,
                                                  const float* __restrict__ accS,
                                                  const float* __restrict__ accI,
                                                  const unsigned short* __restrict__ ib,
                                                  const int* __restrict__ mark,
                                                  const int* __restrict__ uids,
                                                  const int* __restrict__ iids,
                                                  float* __restrict__ out, int batch) {
    int w = (int)((blockIdx.x * (long long)blockDim.x + threadIdx.x) >> 6);
    int lane = threadIdx.x & 63;
    if (w >= batch) return;
    int u = uids[w], it = iids[w];
    long long m = (long long)(mark[u] - 1);
    float uv = 2.0f * bf2f(hb[(long long)u * 64 + lane]) + accS[m * 64 + lane] + accI[m * 64 + lane];
    float vv = 2.0f * bf2f(ib[(long long)it * 64 + lane]);
    float p = uv * vv;
    #pragma unroll
    for (int off = 32; off; off >>= 1) p += __shfl_xor(p, off);
    if (lane == 0) out[w] = 1.0f / (1.0f + __expf(-p));
}

// ---------------- launch ----------------

extern "C" void kernel_launch(void* const* d_in, const int* in_sizes, int n_in,
                              void* d_out, int out_size, void* d_ws, size_t ws_size,
                              hipStream_t stream) {
    const float* user_emb  = (const float*)d_in[0];
    const float* item_emb  = (const float*)d_in[1];
    const int*   soc_rows  = (const int*)d_in[2];
    const int*   soc_cols  = (const int*)d_in[3];
    const float* soc_vals  = (const float*)d_in[4];
    const int*   info_rows = (const int*)d_in[5];
    const int*   info_cols = (const int*)d_in[6];
    const float* info_vals = (const float*)d_in[7];
    const int*   user_ids  = (const int*)d_in[8];
    const int*   item_ids  = (const int*)d_in[9];
    float*       out       = (float*)d_out;

    const int n_user = in_sizes[0] / 64;
    const int n_item = in_sizes[1] / 64;
    const int E_soc  = in_sizes[2];
    const int E_info = in_sizes[5];
    const int batch  = in_sizes[8];

    const int nbinS = (n_user + 63) >> PB;
    int capS = (int)((long long)E_soc * 64 / n_user);
    capS = capS + capS / 4 + 64;
    if (capS > CAPS_LDS) capS = CAPS_LDS;
    int capM = (int)((long long)E_info * 16 / n_user);
    capM = capM + capM / 2 + 64;
    if (capM > CAPM_LDS) capM = CAPM_LDS;

    // ---- workspace layout ----
    char* p = (char*)d_ws;
    auto alloc = [&](size_t bytes) { char* q = p; p += (bytes + 255) & ~size_t(255); return q; };
    int* mark     = (int*)alloc(sizeof(int) * n_user);
    int* n_marked = (int*)alloc(sizeof(int) * 64);
    size_t zero_bytes = (size_t)(p - (char*)d_ws);
    int*  curSoc = (int*)alloc(sizeof(int) * nbinS);
    int*  curMI  = (int*)alloc(sizeof(int) * NBINM_MAX);
    int2* bufSoc = (int2*)alloc(sizeof(int2) * (size_t)nbinS * capS);       // ~33 MB
    int2* bufMI  = (int2*)alloc(sizeof(int2) * (size_t)NBINM_MAX * capM);   // ~7 MB
    unsigned short* ub = (unsigned short*)alloc(sizeof(short) * (size_t)n_user * 64);
    unsigned short* ib = (unsigned short*)alloc(sizeof(short) * (size_t)n_item * 64);
    unsigned short* hb = (unsigned short*)alloc(sizeof(short) * (size_t)n_user * 64);
    float* accS        = (float*)alloc(sizeof(float) * (size_t)batch * 64);
    float* accI        = (float*)alloc(sizeof(float) * (size_t)batch * 64);
    (void)ws_size;

    hipMemsetAsync(d_ws, 0, zero_bytes, stream);

    const int B = 256;
    long long na = (long long)n_user * 64, nbm = (long long)n_item * 64;
    long long c4 = (na > nbm ? na : nbm) / 4;
    conv_kernel<<<(int)((c4 + B - 1) / B), B, 0, stream>>>(user_emb, ub, na, item_emb, ib, nbm);

    mark_init_kernel<<<(batch + B - 1) / B, B, 0, stream>>>(user_ids, mark, n_marked, batch,
                                                            curSoc, nbinS, capS, curMI, capM);

    int gA = (E_soc + CHUNK - 1) / CHUNK;
    partA_soc<<<gA, B, 0, stream>>>(soc_rows, soc_cols, soc_vals, curSoc, bufSoc,
                                    E_soc, nbinS, capS);

    int gAi = (E_info + CHUNK - 1) / CHUNK;
    partA_info<<<gAi, B, 0, stream>>>(info_rows, info_cols, info_vals, E_info,
                                      mark, curMI, bufMI, capM);

    partB_h1<<<nbinS, B, 0, stream>>>(curSoc, bufSoc, ub, hb, n_user, capS);

    partB_accS<<<nbinS, B, 0, stream>>>(mark, curSoc, bufSoc, hb, accS, n_user, capS);

    int gBi = (batch + 15) >> PBM;
    partB_accI<<<gBi, B, 0, stream>>>(n_marked, curMI, bufMI, ib, accI, capM);

    long long t2 = (long long)batch * 64;
    dot_kernel<<<(int)((t2 + B - 1) / B), B, 0, stream>>>(hb, accS, accI, ib, mark,
                                                          user_ids, item_ids, out, batch);
}